// Round 1
// baseline (527.178 us; speedup 1.0000x reference)
//
#include <hip/hip_runtime.h>
#include <hip/hip_bf16.h>
#include <math.h>

#define H_DIM 2048
#define I_DIM 768
#define NEXP  8
#define TTOK  2048
#define BK    32
#define LDK   40   // LDS row stride in elements (80 B, 16B aligned)

typedef __bf16 bf16x8 __attribute__((ext_vector_type(8)));
typedef __bf16 bf16x4 __attribute__((ext_vector_type(4)));
typedef float  f32x4  __attribute__((ext_vector_type(4)));

// ---- workspace layout (bytes) ----
#define WS_COUNTS   0u          // 8 * int
#define WS_OFFSETS  32u         // 8 * int
#define WS_TOK      128u        // NEXP*TTOK int   (65536 B)
#define WS_WGT      65664u      // NEXP*TTOK float (65536 B)
#define WS_XBF      131328u     // TTOK*H_DIM bf16 (8388608 B)
#define WS_HBUF     8519936u    // (4096+128)*I_DIM bf16 (6488064 B)
// total ~15.0 MB

// ---------------- x fp32 -> bf16 ----------------
__global__ void xconv_k(const float* __restrict__ x, __bf16* __restrict__ xb) {
    int i = (blockIdx.x * 256 + threadIdx.x) * 4;
    float4 v = *(const float4*)(x + i);
    bf16x4 o;
    o[0] = (__bf16)v.x; o[1] = (__bf16)v.y; o[2] = (__bf16)v.z; o[3] = (__bf16)v.w;
    *(bf16x4*)(xb + i) = o;
}

// ---------------- router: fp32 logits, top-2, build dispatch lists ----------------
__global__ __launch_bounds__(256) void router_k(const float* __restrict__ x,
                                                const float* __restrict__ wgate,
                                                int* __restrict__ counts,
                                                int* __restrict__ tok_list,
                                                float* __restrict__ wgt) {
    const int t = blockIdx.x;
    const int tid = threadIdx.x;
    float acc[NEXP];
#pragma unroll
    for (int e = 0; e < NEXP; ++e) acc[e] = 0.f;
    const float* xr = x + (size_t)t * H_DIM;
    for (int k = tid; k < H_DIM; k += 256) {
        float xv = xr[k];
#pragma unroll
        for (int e = 0; e < NEXP; ++e) acc[e] += xv * wgate[e * H_DIM + k];
    }
    __shared__ float s_red[NEXP][4];
    __shared__ float s_logit[NEXP];
    const int lane = tid & 63, w = tid >> 6;
#pragma unroll
    for (int e = 0; e < NEXP; ++e) {
        float v = acc[e];
#pragma unroll
        for (int off = 32; off > 0; off >>= 1) v += __shfl_down(v, off, 64);
        if (lane == 0) s_red[e][w] = v;
    }
    __syncthreads();
    if (tid < NEXP) s_logit[tid] = s_red[tid][0] + s_red[tid][1] + s_red[tid][2] + s_red[tid][3];
    __syncthreads();
    if (tid == 0) {
        int i0 = 0; float l0 = s_logit[0];
        for (int e = 1; e < NEXP; ++e) if (s_logit[e] > l0) { l0 = s_logit[e]; i0 = e; }
        int i1 = -1; float l1 = -1e30f;
        for (int e = 0; e < NEXP; ++e) if (e != i0 && s_logit[e] > l1) { l1 = s_logit[e]; i1 = e; }
        // renormalized top-2 softmax: Z cancels
        float w0 = 1.f / (1.f + expf(l1 - l0));
        float w1 = 1.f - w0;
        int p0 = atomicAdd(&counts[i0], 1);
        tok_list[i0 * TTOK + p0] = t; wgt[i0 * TTOK + p0] = w0;
        int p1 = atomicAdd(&counts[i1], 1);
        tok_list[i1 * TTOK + p1] = t; wgt[i1 * TTOK + p1] = w1;
    }
}

// ---------------- exclusive scan over 8 expert counts ----------------
__global__ void scan_k(const int* __restrict__ counts, int* __restrict__ offsets) {
    int r = 0;
    for (int e = 0; e < NEXP; ++e) { offsets[e] = r; r += counts[e]; }
}

// ---------------- GEMM1: h = silu(x@Wg) * (x@Wu), per expert, gathered rows ----------------
// tile: BM=128, BN=64 (both G and U), BK=32; 4 waves in 2x2; wave tile 64x32
__global__ __launch_bounds__(256, 2) void gemm1_k(
    const __bf16* __restrict__ xb, const float* __restrict__ Wg,
    const float* __restrict__ Wu, const int* __restrict__ counts,
    const int* __restrict__ offsets, const int* __restrict__ tok_list,
    __bf16* __restrict__ hbuf) {
    const int e = blockIdx.z;
    const int cnt = counts[e];
    const int m0 = blockIdx.x * 128;
    if (m0 >= cnt) return;
    const int nt = blockIdx.y;     // 0..11
    const int off = offsets[e];
    const int tid = threadIdx.x;

    __shared__ __bf16 sA[128 * LDK];
    __shared__ __bf16 sB[2][64 * LDK];
    __shared__ int s_tok[128];

    if (tid < 128) {
        int m = m0 + tid;
        s_tok[tid] = (m < cnt) ? tok_list[e * TTOK + m] : 0;
    }
    __syncthreads();

    // A staging: thread -> (row, 16-elem chunk pair)
    const int rA = tid >> 1;
    const int ca = (tid & 1) * 16;
    const __bf16* aBase = xb + (size_t)s_tok[rA] * H_DIM + ca;
    __bf16* sAw = &sA[rA * LDK + ca];

    // B staging: 64 cols x 2 matrices x 2 k-halves; convert fp32->bf16, transpose into LDS [n][k]
    const int iB = tid & 63;
    const int matB = (tid >> 6) & 1;
    const int khalf = tid >> 7;
    const float* bBase = (matB ? Wu : Wg) + (size_t)e * (H_DIM * I_DIM)
                         + (size_t)(khalf * 16) * I_DIM + nt * 64 + iB;
    __bf16* sBw = &sB[matB][iB * LDK + khalf * 16];

    const int lane = tid & 63;
    const int w = tid >> 6;
    const int wm = w & 1, wn = w >> 1;
    const int arow = wm * 64 + (lane & 15);
    const int bcol = wn * 32 + (lane & 15);
    const int kg8 = (lane >> 4) * 8;

    f32x4 accG[4][2], accU[4][2];
#pragma unroll
    for (int mf = 0; mf < 4; ++mf)
#pragma unroll
        for (int nf = 0; nf < 2; ++nf) {
            accG[mf][nf] = (f32x4){0.f, 0.f, 0.f, 0.f};
            accU[mf][nf] = (f32x4){0.f, 0.f, 0.f, 0.f};
        }

    for (int kk = 0; kk < H_DIM; kk += BK) {
        uint4 a0 = *(const uint4*)(aBase + kk);
        uint4 a1 = *(const uint4*)(aBase + kk + 8);
        const float* wp = bBase + (size_t)kk * I_DIM;
        bf16x8 tb[2];
#pragma unroll
        for (int j = 0; j < 16; ++j) tb[j >> 3][j & 7] = (__bf16)wp[(size_t)j * I_DIM];
        __syncthreads();
        *(uint4*)sAw = a0;
        *(uint4*)(sAw + 8) = a1;
        *(bf16x8*)sBw = tb[0];
        *(bf16x8*)(sBw + 8) = tb[1];
        __syncthreads();

        bf16x8 af[4], bg[2], bu[2];
#pragma unroll
        for (int mf = 0; mf < 4; ++mf) af[mf] = *(const bf16x8*)&sA[(arow + mf * 16) * LDK + kg8];
#pragma unroll
        for (int nf = 0; nf < 2; ++nf) {
            bg[nf] = *(const bf16x8*)&sB[0][(bcol + nf * 16) * LDK + kg8];
            bu[nf] = *(const bf16x8*)&sB[1][(bcol + nf * 16) * LDK + kg8];
        }
#pragma unroll
        for (int mf = 0; mf < 4; ++mf)
#pragma unroll
            for (int nf = 0; nf < 2; ++nf) {
                accG[mf][nf] = __builtin_amdgcn_mfma_f32_16x16x32_bf16(af[mf], bg[nf], accG[mf][nf], 0, 0, 0);
                accU[mf][nf] = __builtin_amdgcn_mfma_f32_16x16x32_bf16(af[mf], bu[nf], accU[mf][nf], 0, 0, 0);
            }
    }

    // epilogue: silu(g)*u -> bf16 h-buffer (C layout: col=lane&15, row=(lane>>4)*4+reg)
    const int rbase = (lane >> 4) * 4;
    const int ncol = nt * 64 + wn * 32 + (lane & 15);
#pragma unroll
    for (int mf = 0; mf < 4; ++mf) {
#pragma unroll
        for (int reg = 0; reg < 4; ++reg) {
            int m = m0 + wm * 64 + mf * 16 + rbase + reg;
            if (m < cnt) {
                size_t rowbase = (size_t)(off + m) * I_DIM;
#pragma unroll
                for (int nf = 0; nf < 2; ++nf) {
                    float g = accG[mf][nf][reg], u = accU[mf][nf][reg];
                    float h = (g / (1.f + __expf(-g))) * u;
                    hbuf[rowbase + ncol + nf * 16] = (__bf16)h;
                }
            }
        }
    }
}

// ---------------- GEMM2: y = h @ Wd, scatter-add w*y into out ----------------
// tile: BM=128, BN=128, BK=32; 4 waves in 2x2; wave tile 64x64
__global__ __launch_bounds__(256, 2) void gemm2_k(
    const __bf16* __restrict__ hbuf, const float* __restrict__ Wd,
    const int* __restrict__ counts, const int* __restrict__ offsets,
    const int* __restrict__ tok_list, const float* __restrict__ wgt,
    float* __restrict__ out) {
    const int e = blockIdx.z;
    const int cnt = counts[e];
    const int m0 = blockIdx.x * 128;
    if (m0 >= cnt) return;
    const int nt = blockIdx.y;    // 0..15
    const int off = offsets[e];
    const int tid = threadIdx.x;

    __shared__ __bf16 sA[128 * LDK];
    __shared__ __bf16 sB[128 * LDK];
    __shared__ int s_tok[128];
    __shared__ float s_w[128];

    if (tid < 128) {
        int m = m0 + tid;
        if (m < cnt) { s_tok[tid] = tok_list[e * TTOK + m]; s_w[tid] = wgt[e * TTOK + m]; }
        else         { s_tok[tid] = 0;                      s_w[tid] = 0.f; }
    }

    const int rA = tid >> 1;
    const int ca = (tid & 1) * 16;
    const __bf16* aBase = hbuf + (size_t)(off + m0 + rA) * I_DIM + ca;  // hbuf padded by 128 rows
    __bf16* sAw = &sA[rA * LDK + ca];

    const int nB = tid & 127;
    const int khalf = tid >> 7;
    const float* bBase = Wd + (size_t)e * (I_DIM * H_DIM)
                         + (size_t)(khalf * 16) * H_DIM + nt * 128 + nB;
    __bf16* sBw = &sB[nB * LDK + khalf * 16];

    const int lane = tid & 63;
    const int w = tid >> 6;
    const int wm = w & 1, wn = w >> 1;
    const int arow = wm * 64 + (lane & 15);
    const int bcol = wn * 64 + (lane & 15);
    const int kg8 = (lane >> 4) * 8;

    f32x4 acc[4][4];
#pragma unroll
    for (int mf = 0; mf < 4; ++mf)
#pragma unroll
        for (int nf = 0; nf < 4; ++nf) acc[mf][nf] = (f32x4){0.f, 0.f, 0.f, 0.f};

    for (int kk = 0; kk < I_DIM; kk += BK) {
        uint4 a0 = *(const uint4*)(aBase + kk);
        uint4 a1 = *(const uint4*)(aBase + kk + 8);
        const float* wp = bBase + (size_t)kk * H_DIM;
        bf16x8 tb[2];
#pragma unroll
        for (int j = 0; j < 16; ++j) tb[j >> 3][j & 7] = (__bf16)wp[(size_t)j * H_DIM];
        __syncthreads();
        *(uint4*)sAw = a0;
        *(uint4*)(sAw + 8) = a1;
        *(bf16x8*)sBw = tb[0];
        *(bf16x8*)(sBw + 8) = tb[1];
        __syncthreads();

        bf16x8 af[4], bb[4];
#pragma unroll
        for (int mf = 0; mf < 4; ++mf) af[mf] = *(const bf16x8*)&sA[(arow + mf * 16) * LDK + kg8];
#pragma unroll
        for (int nf = 0; nf < 4; ++nf) bb[nf] = *(const bf16x8*)&sB[(bcol + nf * 16) * LDK + kg8];
#pragma unroll
        for (int mf = 0; mf < 4; ++mf)
#pragma unroll
            for (int nf = 0; nf < 4; ++nf)
                acc[mf][nf] = __builtin_amdgcn_mfma_f32_16x16x32_bf16(af[mf], bb[nf], acc[mf][nf], 0, 0, 0);
    }

    const int rbase = (lane >> 4) * 4;
    const int ncol = nt * 128 + wn * 64 + (lane & 15);
#pragma unroll
    for (int mf = 0; mf < 4; ++mf) {
#pragma unroll
        for (int reg = 0; reg < 4; ++reg) {
            int m_loc = wm * 64 + mf * 16 + rbase + reg;
            if (m0 + m_loc < cnt) {
                int tok = s_tok[m_loc];
                float wv = s_w[m_loc];
                float* orow = out + (size_t)tok * H_DIM + ncol;
#pragma unroll
                for (int nf = 0; nf < 4; ++nf)
                    atomicAdd(orow + nf * 16, wv * acc[mf][nf][reg]);
            }
        }
    }
}

extern "C" void kernel_launch(void* const* d_in, const int* in_sizes, int n_in,
                              void* d_out, int out_size, void* d_ws, size_t ws_size,
                              hipStream_t stream) {
    const float* x     = (const float*)d_in[0];
    const float* Wgate = (const float*)d_in[1];
    const float* Wg    = (const float*)d_in[2];
    const float* Wu    = (const float*)d_in[3];
    const float* Wd    = (const float*)d_in[4];
    float* out = (float*)d_out;
    char* ws = (char*)d_ws;

    int*    counts   = (int*)(ws + WS_COUNTS);
    int*    offsets  = (int*)(ws + WS_OFFSETS);
    int*    tok_list = (int*)(ws + WS_TOK);
    float*  wgt      = (float*)(ws + WS_WGT);
    __bf16* xb       = (__bf16*)(ws + WS_XBF);
    __bf16* hbuf     = (__bf16*)(ws + WS_HBUF);

    hipMemsetAsync(counts, 0, 64, stream);
    hipMemsetAsync(d_out, 0, (size_t)TTOK * H_DIM * sizeof(float), stream);

    xconv_k<<<(TTOK * H_DIM / 4) / 256, 256, 0, stream>>>(x, xb);
    router_k<<<TTOK, 256, 0, stream>>>(x, Wgate, counts, tok_list, wgt);
    scan_k<<<1, 1, 0, stream>>>(counts, offsets);
    gemm1_k<<<dim3(16, I_DIM / 64, NEXP), 256, 0, stream>>>(xb, Wg, Wu, counts, offsets, tok_list, hbuf);
    gemm2_k<<<dim3(16, H_DIM / 128, NEXP), 256, 0, stream>>>(hbuf, Wd, counts, offsets, tok_list, wgt, out);
}

// Round 2
// 506.569 us; speedup vs baseline: 1.0407x; 1.0407x over previous
//
#include <hip/hip_runtime.h>
#include <hip/hip_bf16.h>
#include <math.h>

#define H_DIM 2048
#define I_DIM 768
#define NEXP  8
#define TTOK  2048
#define PADK  72    // LDS row stride (elements) for 64-wide k-tiles

typedef __bf16 bf16x8 __attribute__((ext_vector_type(8)));
typedef __bf16 bf16x4 __attribute__((ext_vector_type(4)));
typedef float  f32x4  __attribute__((ext_vector_type(4)));

// ---- workspace layout (bytes) ----
#define WS_COUNTS   0u
#define WS_OFFSETS  32u
#define WS_TOK      128u          // NEXP*TTOK int    (65536)
#define WS_WGTW     65664u        // NEXP*TTOK float  (65536)
#define WS_XBF      131328u       // TTOK*H_DIM bf16  (8388608)
#define WS_HBUF     8519936u      // (4096+64)*I_DIM bf16 (6389760)
#define WS_WG_T     14909696u     // 8*768*2048 bf16  (25165824)
#define WS_WU_T     40075520u     // 8*768*2048 bf16  (25165824)
#define WS_WD_T     65241344u     // 8*2048*768 bf16  (25165824)
// end: 90407168 (~86.2 MB)

// ---------------- x fp32 -> bf16 ----------------
__global__ void xconv_k(const float* __restrict__ x, __bf16* __restrict__ xb) {
    int i = (blockIdx.x * 256 + threadIdx.x) * 4;
    float4 v = *(const float4*)(x + i);
    bf16x4 o;
    o[0] = (__bf16)v.x; o[1] = (__bf16)v.y; o[2] = (__bf16)v.z; o[3] = (__bf16)v.w;
    *(bf16x4*)(xb + i) = o;
}

// ---------------- weight transpose+convert: [E][K][N] fp32 -> [E][N][K] bf16 ----------------
// 64x64 tile, 256 threads
__global__ __launch_bounds__(256) void wtrans_k(const float* __restrict__ in,
                                                __bf16* __restrict__ out,
                                                int K, int N) {
    const int e = blockIdx.z;
    const int k0 = blockIdx.x * 64, n0 = blockIdx.y * 64;
    __shared__ __bf16 sT[64][PADK];   // [n][k]
    const float* ip = in + (size_t)e * K * N;
    const int t = threadIdx.x;
    const int kl = t >> 4;            // 0..15
    const int n4 = (t & 15) * 4;
#pragma unroll
    for (int j = 0; j < 4; ++j) {
        int k = kl + j * 16;
        float4 v = *(const float4*)(ip + (size_t)(k0 + k) * N + n0 + n4);
        sT[n4 + 0][k] = (__bf16)v.x;
        sT[n4 + 1][k] = (__bf16)v.y;
        sT[n4 + 2][k] = (__bf16)v.z;
        sT[n4 + 3][k] = (__bf16)v.w;
    }
    __syncthreads();
    __bf16* op = out + (size_t)e * N * K;
    const int nl = t >> 2;            // 0..63
    const int kc = (t & 3) * 16;
    bf16x8 a = *(const bf16x8*)&sT[nl][kc];
    bf16x8 b = *(const bf16x8*)&sT[nl][kc + 8];
    __bf16* w = op + (size_t)(n0 + nl) * K + k0 + kc;
    *(bf16x8*)w = a;
    *(bf16x8*)(w + 8) = b;
}

// ---------------- router: fp32 logits, top-2, build dispatch lists ----------------
__global__ __launch_bounds__(256) void router_k(const float* __restrict__ x,
                                                const float* __restrict__ wgate,
                                                int* __restrict__ counts,
                                                int* __restrict__ tok_list,
                                                float* __restrict__ wgt) {
    const int t = blockIdx.x;
    const int tid = threadIdx.x;
    float acc[NEXP];
#pragma unroll
    for (int e = 0; e < NEXP; ++e) acc[e] = 0.f;
    const float* xr = x + (size_t)t * H_DIM;
    for (int k = tid; k < H_DIM; k += 256) {
        float xv = xr[k];
#pragma unroll
        for (int e = 0; e < NEXP; ++e) acc[e] += xv * wgate[e * H_DIM + k];
    }
    __shared__ float s_red[NEXP][4];
    __shared__ float s_logit[NEXP];
    const int lane = tid & 63, w = tid >> 6;
#pragma unroll
    for (int e = 0; e < NEXP; ++e) {
        float v = acc[e];
#pragma unroll
        for (int off = 32; off > 0; off >>= 1) v += __shfl_down(v, off, 64);
        if (lane == 0) s_red[e][w] = v;
    }
    __syncthreads();
    if (tid < NEXP) s_logit[tid] = s_red[tid][0] + s_red[tid][1] + s_red[tid][2] + s_red[tid][3];
    __syncthreads();
    if (tid == 0) {
        int i0 = 0; float l0 = s_logit[0];
        for (int e = 1; e < NEXP; ++e) if (s_logit[e] > l0) { l0 = s_logit[e]; i0 = e; }
        int i1 = -1; float l1 = -1e30f;
        for (int e = 0; e < NEXP; ++e) if (e != i0 && s_logit[e] > l1) { l1 = s_logit[e]; i1 = e; }
        float w0 = 1.f / (1.f + expf(l1 - l0));
        float w1 = 1.f - w0;
        int p0 = atomicAdd(&counts[i0], 1);
        tok_list[i0 * TTOK + p0] = t; wgt[i0 * TTOK + p0] = w0;
        int p1 = atomicAdd(&counts[i1], 1);
        tok_list[i1 * TTOK + p1] = t; wgt[i1 * TTOK + p1] = w1;
    }
}

__global__ void scan_k(const int* __restrict__ counts, int* __restrict__ offsets) {
    int r = 0;
    for (int e = 0; e < NEXP; ++e) { offsets[e] = r; r += counts[e]; }
}

// ---------------- GEMM1: h = silu(x@Wg)*(x@Wu) ; BM=64, BN=64(G)+64(U), BK=64 ----------------
__global__ __launch_bounds__(256, 4) void gemm1_k(
    const __bf16* __restrict__ xb, const __bf16* __restrict__ Wgt,
    const __bf16* __restrict__ Wut, const int* __restrict__ counts,
    const int* __restrict__ offsets, const int* __restrict__ tok_list,
    __bf16* __restrict__ hbuf) {
    const int e = blockIdx.z;
    const int cnt = counts[e];
    const int m0 = blockIdx.x * 64;
    if (m0 >= cnt) return;
    const int nt = blockIdx.y;      // 0..11
    const int off = offsets[e];
    const int tid = threadIdx.x;

    __shared__ __bf16 sA[64 * PADK];
    __shared__ __bf16 sG[64 * PADK];
    __shared__ __bf16 sU[64 * PADK];
    __shared__ int s_tok[64];

    if (tid < 64) {
        int m = m0 + tid;
        s_tok[tid] = (m < cnt) ? tok_list[e * TTOK + m] : 0;
    }
    __syncthreads();

    // staging map: row = tid>>2 (0..63), kc = (tid&3)*16
    const int row = tid >> 2;
    const int kc = (tid & 3) * 16;
    const __bf16* aB = xb + (size_t)s_tok[row] * H_DIM + kc;
    const __bf16* gB = Wgt + ((size_t)e * I_DIM + nt * 64 + row) * H_DIM + kc;
    const __bf16* uB = Wut + ((size_t)e * I_DIM + nt * 64 + row) * H_DIM + kc;
    __bf16* sAw = &sA[row * PADK + kc];
    __bf16* sGw = &sG[row * PADK + kc];
    __bf16* sUw = &sU[row * PADK + kc];

    const int lane = tid & 63;
    const int w = tid >> 6;
    const int wm = w & 1, wn = w >> 1;
    const int arow = wm * 32 + (lane & 15);
    const int bcol = wn * 32 + (lane & 15);
    const int kg8 = (lane >> 4) * 8;

    f32x4 accG[2][2], accU[2][2];
#pragma unroll
    for (int mf = 0; mf < 2; ++mf)
#pragma unroll
        for (int nf = 0; nf < 2; ++nf) {
            accG[mf][nf] = (f32x4){0.f, 0.f, 0.f, 0.f};
            accU[mf][nf] = (f32x4){0.f, 0.f, 0.f, 0.f};
        }

    for (int kk = 0; kk < H_DIM; kk += 64) {
        bf16x8 a0 = *(const bf16x8*)(aB + kk);
        bf16x8 a1 = *(const bf16x8*)(aB + kk + 8);
        bf16x8 g0 = *(const bf16x8*)(gB + kk);
        bf16x8 g1 = *(const bf16x8*)(gB + kk + 8);
        bf16x8 u0 = *(const bf16x8*)(uB + kk);
        bf16x8 u1 = *(const bf16x8*)(uB + kk + 8);
        __syncthreads();
        *(bf16x8*)sAw = a0; *(bf16x8*)(sAw + 8) = a1;
        *(bf16x8*)sGw = g0; *(bf16x8*)(sGw + 8) = g1;
        *(bf16x8*)sUw = u0; *(bf16x8*)(sUw + 8) = u1;
        __syncthreads();

#pragma unroll
        for (int c = 0; c < 2; ++c) {
            bf16x8 af[2], bg[2], bu[2];
#pragma unroll
            for (int mf = 0; mf < 2; ++mf)
                af[mf] = *(const bf16x8*)&sA[(arow + mf * 16) * PADK + c * 32 + kg8];
#pragma unroll
            for (int nf = 0; nf < 2; ++nf) {
                bg[nf] = *(const bf16x8*)&sG[(bcol + nf * 16) * PADK + c * 32 + kg8];
                bu[nf] = *(const bf16x8*)&sU[(bcol + nf * 16) * PADK + c * 32 + kg8];
            }
#pragma unroll
            for (int mf = 0; mf < 2; ++mf)
#pragma unroll
                for (int nf = 0; nf < 2; ++nf) {
                    accG[mf][nf] = __builtin_amdgcn_mfma_f32_16x16x32_bf16(af[mf], bg[nf], accG[mf][nf], 0, 0, 0);
                    accU[mf][nf] = __builtin_amdgcn_mfma_f32_16x16x32_bf16(af[mf], bu[nf], accU[mf][nf], 0, 0, 0);
                }
        }
    }

    // epilogue: silu(g)*u -> bf16 (C layout: col=lane&15, row=(lane>>4)*4+reg)
    const int rbase = (lane >> 4) * 4;
    const int ncol = nt * 64 + wn * 32 + (lane & 15);
#pragma unroll
    for (int mf = 0; mf < 2; ++mf) {
#pragma unroll
        for (int reg = 0; reg < 4; ++reg) {
            int m = m0 + wm * 32 + mf * 16 + rbase + reg;
            if (m < cnt) {
                size_t rowbase = (size_t)(off + m) * I_DIM;
#pragma unroll
                for (int nf = 0; nf < 2; ++nf) {
                    float g = accG[mf][nf][reg], u = accU[mf][nf][reg];
                    float h = (g / (1.f + __expf(-g))) * u;
                    hbuf[rowbase + ncol + nf * 16] = (__bf16)h;
                }
            }
        }
    }
}

// ---------------- GEMM2: y = h @ Wd^T-packed, scatter-add w*y ; BM=64, BN=128, BK=64 ----------------
__global__ __launch_bounds__(256, 4) void gemm2_k(
    const __bf16* __restrict__ hbuf, const __bf16* __restrict__ Wdt,
    const int* __restrict__ counts, const int* __restrict__ offsets,
    const int* __restrict__ tok_list, const float* __restrict__ wgt,
    float* __restrict__ out) {
    const int e = blockIdx.z;
    const int cnt = counts[e];
    const int m0 = blockIdx.x * 64;
    if (m0 >= cnt) return;
    const int nt = blockIdx.y;    // 0..15
    const int off = offsets[e];
    const int tid = threadIdx.x;

    __shared__ __bf16 sA[64 * PADK];
    __shared__ __bf16 sB[128 * PADK];
    __shared__ int s_tok[64];
    __shared__ float s_w[64];

    if (tid < 64) {
        int m = m0 + tid;
        if (m < cnt) { s_tok[tid] = tok_list[e * TTOK + m]; s_w[tid] = wgt[e * TTOK + m]; }
        else         { s_tok[tid] = 0;                      s_w[tid] = 0.f; }
    }

    const int rowA = tid >> 2;
    const int kcA = (tid & 3) * 16;
    const __bf16* aB = hbuf + (size_t)(off + m0 + rowA) * I_DIM + kcA;
    __bf16* sAw = &sA[rowA * PADK + kcA];

    const int rowB = tid >> 1;           // 0..127
    const int kcB = (tid & 1) * 32;
    const __bf16* bB = Wdt + ((size_t)e * H_DIM + nt * 128 + rowB) * I_DIM + kcB;
    __bf16* sBw = &sB[rowB * PADK + kcB];

    const int lane = tid & 63;
    const int w = tid >> 6;
    const int wm = w & 1, wn = w >> 1;
    const int arow = wm * 32 + (lane & 15);
    const int bcol = wn * 64 + (lane & 15);
    const int kg8 = (lane >> 4) * 8;

    f32x4 acc[2][4];
#pragma unroll
    for (int mf = 0; mf < 2; ++mf)
#pragma unroll
        for (int nf = 0; nf < 4; ++nf) acc[mf][nf] = (f32x4){0.f, 0.f, 0.f, 0.f};

    for (int kk = 0; kk < I_DIM; kk += 64) {
        bf16x8 a0 = *(const bf16x8*)(aB + kk);
        bf16x8 a1 = *(const bf16x8*)(aB + kk + 8);
        bf16x8 b0 = *(const bf16x8*)(bB + kk);
        bf16x8 b1 = *(const bf16x8*)(bB + kk + 8);
        bf16x8 b2 = *(const bf16x8*)(bB + kk + 16);
        bf16x8 b3 = *(const bf16x8*)(bB + kk + 24);
        __syncthreads();
        *(bf16x8*)sAw = a0; *(bf16x8*)(sAw + 8) = a1;
        *(bf16x8*)sBw = b0; *(bf16x8*)(sBw + 8) = b1;
        *(bf16x8*)(sBw + 16) = b2; *(bf16x8*)(sBw + 24) = b3;
        __syncthreads();

#pragma unroll
        for (int c = 0; c < 2; ++c) {
            bf16x8 af[2], bb[4];
#pragma unroll
            for (int mf = 0; mf < 2; ++mf)
                af[mf] = *(const bf16x8*)&sA[(arow + mf * 16) * PADK + c * 32 + kg8];
#pragma unroll
            for (int nf = 0; nf < 4; ++nf)
                bb[nf] = *(const bf16x8*)&sB[(bcol + nf * 16) * PADK + c * 32 + kg8];
#pragma unroll
            for (int mf = 0; mf < 2; ++mf)
#pragma unroll
                for (int nf = 0; nf < 4; ++nf)
                    acc[mf][nf] = __builtin_amdgcn_mfma_f32_16x16x32_bf16(af[mf], bb[nf], acc[mf][nf], 0, 0, 0);
        }
    }

    const int rbase = (lane >> 4) * 4;
    const int ncol = nt * 128 + wn * 64 + (lane & 15);
#pragma unroll
    for (int mf = 0; mf < 2; ++mf) {
#pragma unroll
        for (int reg = 0; reg < 4; ++reg) {
            int m_loc = wm * 32 + mf * 16 + rbase + reg;
            if (m0 + m_loc < cnt) {
                int tok = s_tok[m_loc];
                float wv = s_w[m_loc];
                float* orow = out + (size_t)tok * H_DIM + ncol;
#pragma unroll
                for (int nf = 0; nf < 4; ++nf)
                    atomicAdd(orow + nf * 16, wv * acc[mf][nf][reg]);
            }
        }
    }
}

extern "C" void kernel_launch(void* const* d_in, const int* in_sizes, int n_in,
                              void* d_out, int out_size, void* d_ws, size_t ws_size,
                              hipStream_t stream) {
    const float* x     = (const float*)d_in[0];
    const float* Wgate = (const float*)d_in[1];
    const float* Wg    = (const float*)d_in[2];
    const float* Wu    = (const float*)d_in[3];
    const float* Wd    = (const float*)d_in[4];
    float* out = (float*)d_out;
    char* ws = (char*)d_ws;

    int*    counts   = (int*)(ws + WS_COUNTS);
    int*    offsets  = (int*)(ws + WS_OFFSETS);
    int*    tok_list = (int*)(ws + WS_TOK);
    float*  wgt      = (float*)(ws + WS_WGTW);
    __bf16* xb       = (__bf16*)(ws + WS_XBF);
    __bf16* hbuf     = (__bf16*)(ws + WS_HBUF);
    __bf16* Wg_t     = (__bf16*)(ws + WS_WG_T);
    __bf16* Wu_t     = (__bf16*)(ws + WS_WU_T);
    __bf16* Wd_t     = (__bf16*)(ws + WS_WD_T);

    hipMemsetAsync(counts, 0, 64, stream);
    hipMemsetAsync(d_out, 0, (size_t)TTOK * H_DIM * sizeof(float), stream);

    xconv_k<<<(TTOK * H_DIM / 4) / 256, 256, 0, stream>>>(x, xb);
    router_k<<<TTOK, 256, 0, stream>>>(x, Wgate, counts, tok_list, wgt);
    scan_k<<<1, 1, 0, stream>>>(counts, offsets);
    // Wg,Wu: [E][2048][768] -> [E][768][2048] ; Wd: [E][768][2048] -> [E][2048][768]
    wtrans_k<<<dim3(H_DIM / 64, I_DIM / 64, NEXP), 256, 0, stream>>>(Wg, Wg_t, H_DIM, I_DIM);
    wtrans_k<<<dim3(H_DIM / 64, I_DIM / 64, NEXP), 256, 0, stream>>>(Wu, Wu_t, H_DIM, I_DIM);
    wtrans_k<<<dim3(I_DIM / 64, H_DIM / 64, NEXP), 256, 0, stream>>>(Wd, Wd_t, I_DIM, H_DIM);
    gemm1_k<<<dim3(32, I_DIM / 64, NEXP), 256, 0, stream>>>(xb, Wg_t, Wu_t, counts, offsets, tok_list, hbuf);
    gemm2_k<<<dim3(32, H_DIM / 128, NEXP), 256, 0, stream>>>(hbuf, Wd_t, counts, offsets, tok_list, wgt, out);
}

// Round 3
// 460.306 us; speedup vs baseline: 1.1453x; 1.1005x over previous
//
#include <hip/hip_runtime.h>
#include <hip/hip_bf16.h>
#include <math.h>

#define H_DIM 2048
#define I_DIM 768
#define NEXP  8
#define TTOK  2048

typedef __bf16 bf16x8 __attribute__((ext_vector_type(8)));
typedef __bf16 bf16x4 __attribute__((ext_vector_type(4)));
typedef float  f32x4  __attribute__((ext_vector_type(4)));

// ---- workspace layout (bytes) ----
#define WS_COUNTS   0u
#define WS_TOK      128u          // NEXP*TTOK int    (65536)
#define WS_WGTW     65664u        // NEXP*TTOK float  (65536)
#define WS_XBF      131328u       // TTOK*H_DIM bf16  (8388608)
#define WS_HBUF     8519936u      // (4096+128)*I_DIM bf16 (6488064)
#define WS_WG_T     15008000u     // 8*768*2048 bf16  (25165824)
#define WS_WU_T     40173824u     // 8*768*2048 bf16  (25165824)
#define WS_WD_T     65339648u     // 8*2048*768 bf16  (25165824)
// end: 90505472 (~86.3 MB)

// async global->LDS, 16B per lane; LDS dest is wave-uniform base + lane*16
__device__ __forceinline__ void gl2l(const __bf16* g, __bf16* l) {
    __builtin_amdgcn_global_load_lds(
        (const __attribute__((address_space(1))) unsigned int*)g,
        (__attribute__((address_space(3))) unsigned int*)l, 16, 0, 0);
}

// ---------------- x fp32 -> bf16 ----------------
__global__ void xconv_k(const float* __restrict__ x, __bf16* __restrict__ xb) {
    int i = (blockIdx.x * 256 + threadIdx.x) * 4;
    float4 v = *(const float4*)(x + i);
    bf16x4 o;
    o[0] = (__bf16)v.x; o[1] = (__bf16)v.y; o[2] = (__bf16)v.z; o[3] = (__bf16)v.w;
    *(bf16x4*)(xb + i) = o;
}

// ---------------- weight transpose+convert: [E][K][N] fp32 -> [E][N][K] bf16 ----------------
__global__ __launch_bounds__(256) void wtrans_k(const float* __restrict__ in,
                                                __bf16* __restrict__ out,
                                                int K, int N) {
    const int e = blockIdx.z;
    const int k0 = blockIdx.x * 64, n0 = blockIdx.y * 64;
    __shared__ float sT[64 * 65];
    const float* ip = in + (size_t)e * K * N;
    const int t = threadIdx.x;
    const int kl = t >> 4;            // 0..15
    const int n4 = (t & 15) * 4;
#pragma unroll
    for (int j = 0; j < 4; ++j) {
        int k = kl + j * 16;
        float4 v = *(const float4*)(ip + (size_t)(k0 + k) * N + n0 + n4);
        sT[(n4 + 0) * 65 + k] = v.x;
        sT[(n4 + 1) * 65 + k] = v.y;
        sT[(n4 + 2) * 65 + k] = v.z;
        sT[(n4 + 3) * 65 + k] = v.w;
    }
    __syncthreads();
    const int n = t >> 2;             // 0..63
    const int kc = (t & 3) * 16;
    bf16x8 o0, o1;
#pragma unroll
    for (int j = 0; j < 8; ++j) {
        o0[j] = (__bf16)sT[n * 65 + kc + j];
        o1[j] = (__bf16)sT[n * 65 + kc + 8 + j];
    }
    __bf16* op = out + (size_t)e * N * K + (size_t)(n0 + n) * K + k0 + kc;
    *(bf16x8*)op = o0;
    *(bf16x8*)(op + 8) = o1;
}

// ---------------- router ----------------
__global__ __launch_bounds__(256) void router_k(const float* __restrict__ x,
                                                const float* __restrict__ wgate,
                                                int* __restrict__ counts,
                                                int* __restrict__ tok_list,
                                                float* __restrict__ wgt) {
    const int t = blockIdx.x;
    const int tid = threadIdx.x;
    float acc[NEXP];
#pragma unroll
    for (int e = 0; e < NEXP; ++e) acc[e] = 0.f;
    const float* xr = x + (size_t)t * H_DIM;
    for (int k = tid; k < H_DIM; k += 256) {
        float xv = xr[k];
#pragma unroll
        for (int e = 0; e < NEXP; ++e) acc[e] += xv * wgate[e * H_DIM + k];
    }
    __shared__ float s_red[NEXP][4];
    __shared__ float s_logit[NEXP];
    const int lane = tid & 63, w = tid >> 6;
#pragma unroll
    for (int e = 0; e < NEXP; ++e) {
        float v = acc[e];
#pragma unroll
        for (int off = 32; off > 0; off >>= 1) v += __shfl_down(v, off, 64);
        if (lane == 0) s_red[e][w] = v;
    }
    __syncthreads();
    if (tid < NEXP) s_logit[tid] = s_red[tid][0] + s_red[tid][1] + s_red[tid][2] + s_red[tid][3];
    __syncthreads();
    if (tid == 0) {
        int i0 = 0; float l0 = s_logit[0];
        for (int e = 1; e < NEXP; ++e) if (s_logit[e] > l0) { l0 = s_logit[e]; i0 = e; }
        int i1 = -1; float l1 = -1e30f;
        for (int e = 0; e < NEXP; ++e) if (e != i0 && s_logit[e] > l1) { l1 = s_logit[e]; i1 = e; }
        float w0 = 1.f / (1.f + expf(l1 - l0));
        float w1 = 1.f - w0;
        int p0 = atomicAdd(&counts[i0], 1);
        tok_list[i0 * TTOK + p0] = t; wgt[i0 * TTOK + p0] = w0;
        int p1 = atomicAdd(&counts[i1], 1);
        tok_list[i1 * TTOK + p1] = t; wgt[i1 * TTOK + p1] = w1;
    }
}

// ---------------- GEMM1: h = silu(x@Wg)*(x@Wu); BM=128, BN=64 (G and U), BK=64 ----------------
// m97-style: global_load_lds staging, XOR-swizzled LDS, 4 waves in 2x2, wave tile 64m x 32n x {G,U}
__global__ __launch_bounds__(256) void gemm1_k(
    const __bf16* __restrict__ xb, const __bf16* __restrict__ Wgt,
    const __bf16* __restrict__ Wut, const int* __restrict__ counts,
    const int* __restrict__ tok_list, __bf16* __restrict__ hbuf) {
    const int e = blockIdx.z;
    const int cnt = counts[e];
    const int m0 = blockIdx.x * 128;
    if (m0 >= cnt) return;
    const int nt = blockIdx.y;      // 0..11
    const int tid = threadIdx.x;
    const int lane = tid & 63, w = tid >> 6;

    __shared__ __bf16 sA[128 * 64];
    __shared__ __bf16 sG[64 * 64];
    __shared__ __bf16 sU[64 * 64];
    __shared__ int s_tok[128];
    __shared__ int s_off;

    if (tid == 0) { int o = 0; for (int j = 0; j < e; ++j) o += counts[j]; s_off = o; }
    if (tid < 128) {
        int m = m0 + tid;
        s_tok[tid] = tok_list[e * TTOK + (m < cnt ? m : cnt - 1)];
    }
    __syncthreads();
    const int off = s_off;

    // staging constants: per wave-issue 8 rows x 64k; logical chunk c stored at slot c^(row&7)
    const int lr = lane >> 3;              // row within 8-row group
    const int gofs = ((lane & 7) ^ lr) * 8; // logical chunk element offset for this lane's slot
    const __bf16* pA[4]; __bf16* lA[4];
#pragma unroll
    for (int i = 0; i < 4; ++i) {
        int r = w * 8 + i * 32 + lr;
        pA[i] = xb + (size_t)s_tok[r] * H_DIM + gofs;
        lA[i] = sA + (w * 8 + i * 32) * 64;
    }
    const __bf16* pG[2]; const __bf16* pU[2]; __bf16 *lG[2], *lU[2];
#pragma unroll
    for (int i = 0; i < 2; ++i) {
        int r = w * 8 + i * 32 + lr;
        size_t grow = (size_t)e * I_DIM + nt * 64 + r;
        pG[i] = Wgt + grow * H_DIM + gofs;
        pU[i] = Wut + grow * H_DIM + gofs;
        lG[i] = sG + (w * 8 + i * 32) * 64;
        lU[i] = sU + (w * 8 + i * 32) * 64;
    }

    const int wm = w & 1, wn = w >> 1;
    const int l15 = lane & 15, l7 = lane & 7, kq = lane >> 4;
    int swzk[2];
    swzk[0] = (kq ^ l7) * 8;
    swzk[1] = ((kq + 4) ^ l7) * 8;
    const int arow = wm * 64 + l15;
    const int brow = wn * 32 + l15;

    f32x4 accG[4][2], accU[4][2];
#pragma unroll
    for (int mf = 0; mf < 4; ++mf)
#pragma unroll
        for (int nf = 0; nf < 2; ++nf) {
            accG[mf][nf] = (f32x4){0.f, 0.f, 0.f, 0.f};
            accU[mf][nf] = (f32x4){0.f, 0.f, 0.f, 0.f};
        }

    for (int kk = 0; kk < H_DIM; kk += 64) {
#pragma unroll
        for (int i = 0; i < 4; ++i) gl2l(pA[i] + kk, lA[i]);
#pragma unroll
        for (int i = 0; i < 2; ++i) { gl2l(pG[i] + kk, lG[i]); gl2l(pU[i] + kk, lU[i]); }
        __syncthreads();   // compiler drains vmcnt before barrier -> LDS tile valid
#pragma unroll
        for (int ch = 0; ch < 2; ++ch) {
            bf16x8 af[4], bg[2], bu[2];
#pragma unroll
            for (int mf = 0; mf < 4; ++mf)
                af[mf] = *(const bf16x8*)(sA + (arow + mf * 16) * 64 + swzk[ch]);
#pragma unroll
            for (int nf = 0; nf < 2; ++nf) {
                bg[nf] = *(const bf16x8*)(sG + (brow + nf * 16) * 64 + swzk[ch]);
                bu[nf] = *(const bf16x8*)(sU + (brow + nf * 16) * 64 + swzk[ch]);
            }
#pragma unroll
            for (int mf = 0; mf < 4; ++mf)
#pragma unroll
                for (int nf = 0; nf < 2; ++nf) {
                    accG[mf][nf] = __builtin_amdgcn_mfma_f32_16x16x32_bf16(af[mf], bg[nf], accG[mf][nf], 0, 0, 0);
                    accU[mf][nf] = __builtin_amdgcn_mfma_f32_16x16x32_bf16(af[mf], bu[nf], accU[mf][nf], 0, 0, 0);
                }
        }
        __syncthreads();
    }

    // epilogue: silu(g)*u -> bf16 (C layout: col=lane&15, row=(lane>>4)*4+reg)
#pragma unroll
    for (int mf = 0; mf < 4; ++mf) {
#pragma unroll
        for (int reg = 0; reg < 4; ++reg) {
            int m = m0 + wm * 64 + mf * 16 + kq * 4 + reg;
            if (m < cnt) {
                size_t rowbase = (size_t)(off + m) * I_DIM;
                int ncol = nt * 64 + wn * 32 + l15;
#pragma unroll
                for (int nf = 0; nf < 2; ++nf) {
                    float g = accG[mf][nf][reg], u = accU[mf][nf][reg];
                    float h = (g / (1.f + __expf(-g))) * u;
                    hbuf[rowbase + ncol + nf * 16] = (__bf16)h;
                }
            }
        }
    }
}

// ---------------- GEMM2: y = h @ Wd_t, scatter-add w*y; BM=128, BN=128, BK=64 ----------------
__global__ __launch_bounds__(256) void gemm2_k(
    const __bf16* __restrict__ hbuf, const __bf16* __restrict__ Wdt,
    const int* __restrict__ counts, const int* __restrict__ tok_list,
    const float* __restrict__ wgt, float* __restrict__ out) {
    const int e = blockIdx.z;
    const int cnt = counts[e];
    const int m0 = blockIdx.x * 128;
    if (m0 >= cnt) return;
    const int nt = blockIdx.y;    // 0..15
    const int tid = threadIdx.x;
    const int lane = tid & 63, w = tid >> 6;

    __shared__ __bf16 sA[128 * 64];
    __shared__ __bf16 sB[128 * 64];
    __shared__ int s_tok[128];
    __shared__ float s_w[128];
    __shared__ int s_off;

    if (tid == 0) { int o = 0; for (int j = 0; j < e; ++j) o += counts[j]; s_off = o; }
    if (tid < 128) {
        int m = m0 + tid;
        if (m < cnt) { s_tok[tid] = tok_list[e * TTOK + m]; s_w[tid] = wgt[e * TTOK + m]; }
        else         { s_tok[tid] = 0;                      s_w[tid] = 0.f; }
    }
    __syncthreads();
    const int off = s_off;

    const int lr = lane >> 3;
    const int gofs = ((lane & 7) ^ lr) * 8;
    const __bf16* pA[4]; __bf16* lA[4];
    const __bf16* pB[4]; __bf16* lB[4];
#pragma unroll
    for (int i = 0; i < 4; ++i) {
        int r = w * 8 + i * 32 + lr;
        pA[i] = hbuf + (size_t)(off + m0 + r) * I_DIM + gofs;
        lA[i] = sA + (w * 8 + i * 32) * 64;
        pB[i] = Wdt + ((size_t)e * H_DIM + nt * 128 + r) * I_DIM + gofs;
        lB[i] = sB + (w * 8 + i * 32) * 64;
    }

    const int wm = w & 1, wn = w >> 1;
    const int l15 = lane & 15, l7 = lane & 7, kq = lane >> 4;
    int swzk[2];
    swzk[0] = (kq ^ l7) * 8;
    swzk[1] = ((kq + 4) ^ l7) * 8;
    const int arow = wm * 64 + l15;
    const int brow = wn * 64 + l15;

    f32x4 acc[4][4];
#pragma unroll
    for (int mf = 0; mf < 4; ++mf)
#pragma unroll
        for (int nf = 0; nf < 4; ++nf) acc[mf][nf] = (f32x4){0.f, 0.f, 0.f, 0.f};

    for (int kk = 0; kk < I_DIM; kk += 64) {
#pragma unroll
        for (int i = 0; i < 4; ++i) { gl2l(pA[i] + kk, lA[i]); gl2l(pB[i] + kk, lB[i]); }
        __syncthreads();
#pragma unroll
        for (int ch = 0; ch < 2; ++ch) {
            bf16x8 af[4], bb[4];
#pragma unroll
            for (int mf = 0; mf < 4; ++mf)
                af[mf] = *(const bf16x8*)(sA + (arow + mf * 16) * 64 + swzk[ch]);
#pragma unroll
            for (int nf = 0; nf < 4; ++nf)
                bb[nf] = *(const bf16x8*)(sB + (brow + nf * 16) * 64 + swzk[ch]);
#pragma unroll
            for (int mf = 0; mf < 4; ++mf)
#pragma unroll
                for (int nf = 0; nf < 4; ++nf)
                    acc[mf][nf] = __builtin_amdgcn_mfma_f32_16x16x32_bf16(af[mf], bb[nf], acc[mf][nf], 0, 0, 0);
        }
        __syncthreads();
    }

#pragma unroll
    for (int mf = 0; mf < 4; ++mf) {
#pragma unroll
        for (int reg = 0; reg < 4; ++reg) {
            int m_loc = wm * 64 + mf * 16 + kq * 4 + reg;
            if (m0 + m_loc < cnt) {
                int tok = s_tok[m_loc];
                float wv = s_w[m_loc];
                float* orow = out + (size_t)tok * H_DIM + nt * 128 + wn * 64 + l15;
#pragma unroll
                for (int nf = 0; nf < 4; ++nf)
                    atomicAdd(orow + nf * 16, wv * acc[mf][nf][reg]);
            }
        }
    }
}

extern "C" void kernel_launch(void* const* d_in, const int* in_sizes, int n_in,
                              void* d_out, int out_size, void* d_ws, size_t ws_size,
                              hipStream_t stream) {
    const float* x     = (const float*)d_in[0];
    const float* Wgate = (const float*)d_in[1];
    const float* Wg    = (const float*)d_in[2];
    const float* Wu    = (const float*)d_in[3];
    const float* Wd    = (const float*)d_in[4];
    float* out = (float*)d_out;
    char* ws = (char*)d_ws;

    int*    counts   = (int*)(ws + WS_COUNTS);
    int*    tok_list = (int*)(ws + WS_TOK);
    float*  wgt      = (float*)(ws + WS_WGTW);
    __bf16* xb       = (__bf16*)(ws + WS_XBF);
    __bf16* hbuf     = (__bf16*)(ws + WS_HBUF);
    __bf16* Wg_t     = (__bf16*)(ws + WS_WG_T);
    __bf16* Wu_t     = (__bf16*)(ws + WS_WU_T);
    __bf16* Wd_t     = (__bf16*)(ws + WS_WD_T);

    hipMemsetAsync(counts, 0, 32, stream);
    hipMemsetAsync(d_out, 0, (size_t)TTOK * H_DIM * sizeof(float), stream);

    xconv_k<<<(TTOK * H_DIM / 4) / 256, 256, 0, stream>>>(x, xb);
    router_k<<<TTOK, 256, 0, stream>>>(x, Wgate, counts, tok_list, wgt);
    // Wg,Wu: [E][2048][768] -> [E][768][2048] ; Wd: [E][768][2048] -> [E][2048][768]
    wtrans_k<<<dim3(H_DIM / 64, I_DIM / 64, NEXP), 256, 0, stream>>>(Wg, Wg_t, H_DIM, I_DIM);
    wtrans_k<<<dim3(H_DIM / 64, I_DIM / 64, NEXP), 256, 0, stream>>>(Wu, Wu_t, H_DIM, I_DIM);
    wtrans_k<<<dim3(I_DIM / 64, H_DIM / 64, NEXP), 256, 0, stream>>>(Wd, Wd_t, I_DIM, H_DIM);
    gemm1_k<<<dim3(16, I_DIM / 64, NEXP), 256, 0, stream>>>(xb, Wg_t, Wu_t, counts, tok_list, hbuf);
    gemm2_k<<<dim3(16, H_DIM / 128, NEXP), 256, 0, stream>>>(hbuf, Wd_t, counts, tok_list, wgt, out);
}